// Round 9
// baseline (269.248 us; speedup 1.0000x reference)
//
#include <hip/hip_runtime.h>
#include <math.h>

// B=32, C=12, H=64, W=64, hidden=128, cond_c=4, out_spline=276 (pad->288=12*24)
// NUM_BINS=8, TAIL=3.0, MBW=MBH=MD=0.001

#define NPIX 4096
#define NY   1572864

typedef _Float16 half8 __attribute__((ext_vector_type(8)));
typedef _Float16 half4 __attribute__((ext_vector_type(4)));
typedef float f32x4 __attribute__((ext_vector_type(4)));

// async global->LDS, 16B per lane: HW writes LDS base + lane*16; lds base wave-uniform
#define ASYNC16(gsrc, ldst) \
  __builtin_amdgcn_global_load_lds((const __attribute__((address_space(1))) unsigned int*)(gsrc), \
                                   (__attribute__((address_space(3))) unsigned int*)(ldst), 16, 0, 0)

// XOR chunk swizzle: LDS slot s holds global 16B-chunk swz(s). Self-inverse.
// Read side: quad ^= (row&3). Breaks the 64B-stride 8-way bank conflicts.
__device__ __forceinline__ int swz(int s) { return (s & ~3) | ((s ^ (s >> 2)) & 3); }

// h2p layout: [b][cc=ci/32][pp=66*66][ci%32] fp16, halo ring of zeros
#define H2P_PLANE 4356            // 66*66
#define H2P_IDX(b, cc, pp) ((((size_t)(b) * 4 + (cc)) * H2P_PLANE + (pp)) << 5)
// xh layout: [b][pp=66*66][32] fp16 (ci<12 x, 12..15 cond, >=16 zero; halo zero)
#define XH_IDX(b, pp) (((size_t)(b) * H2P_PLANE + (pp)) << 5)

// ---------------------------------------------------------------------------
// setup: weight packs + logdet init + xh pack (prep+xh fused; disjoint outputs)
//   w1 (128,16,3,3)  -> w1h[(t*128+oc)*32 + k]   k=ci<16 real, k>=16 zero   fp16
//   w2 (128,128,1,1) -> w2h[(ks*128+oc)*32 + km]  (ci=ks*32+km)             fp16
//   w3 (276,128,3,3) -> w3h[((t*4+cc)*288 + oc')*32 + cim]                  fp16
//                       oc' = c*24 + j (j<23 real, j=23 zero pad)
// ---------------------------------------------------------------------------
__global__ __launch_bounds__(256) void setup_k(
    const float* __restrict__ w1, const float* __restrict__ w2,
    const float* __restrict__ w3, _Float16* __restrict__ w1h,
    _Float16* __restrict__ w2h, _Float16* __restrict__ w3h,
    const float* __restrict__ logdet, float* __restrict__ ld_out,
    const float* __restrict__ x, const float* __restrict__ cond,
    _Float16* __restrict__ xh)
{
    const int i = blockIdx.x * 256 + threadIdx.x;   // < 331776
    if (i < 36864) {                     // w1h
        int k = i & 31, oc = (i >> 5) & 127, t = i >> 12;
        w1h[i] = (_Float16)((k < 16) ? w1[(oc * 16 + k) * 9 + t] : 0.f);
    }
    if (i < 16384) {                     // w2h
        int km = i & 31, oc = (i >> 5) & 127, ks = i >> 12;
        w2h[i] = (_Float16)w2[oc * 128 + ks * 32 + km];
    }
    {   // w3h
        int cim = i & 31;
        int oc = (i >> 5) % 288;
        int tc = i / (288 * 32);        // 0..35
        int t = tc >> 2, cc = tc & 3;
        int c = oc / 24, j = oc % 24;
        int ci = cc * 32 + cim;
        float v = (j < 23) ? w3[((c * 23 + j) * 128 + ci) * 9 + t] : 0.f;
        w3h[i] = (_Float16)v;
    }
    if (i < 32) ld_out[i] = logdet[i];
    if (i < 139392) {                    // xh pack (32*4356)
        const int b = i / H2P_PLANE, pp = i % H2P_PLANE;
        const int pr = pp / 66, pc = pp % 66;
        const bool interior = (pr >= 1) && (pr <= 64) && (pc >= 1) && (pc <= 64);
        _Float16 v[32];
#pragma unroll
        for (int ci = 0; ci < 32; ++ci) v[ci] = (_Float16)0.f;
        if (interior) {
            const int p = (pr - 1) * 64 + (pc - 1);
#pragma unroll
            for (int ci = 0; ci < 12; ++ci)
                v[ci] = (_Float16)x[((size_t)(b * 12 + ci) << 12) + p];
#pragma unroll
            for (int ci = 0; ci < 4; ++ci)
                v[12 + ci] = (_Float16)cond[((size_t)(b * 4 + ci) << 12) + p];
        }
        _Float16* dst = xh + ((size_t)i << 5);
#pragma unroll
        for (int q = 0; q < 4; ++q) *(f32x4*)(dst + q * 8) = *(f32x4*)(v + q * 8);
    }
}

// ---------------------------------------------------------------------------
// conv1 as implicit-GEMM MFMA: M=pixels, N=128 oc, K=9 taps x 32 (16 real ci).
// Entire w1h (72 KB) staged in LDS once; zero K-loop barriers after that.
// ---------------------------------------------------------------------------
__global__ __launch_bounds__(256, 2) void conv1_k(
    const _Float16* __restrict__ xh, const _Float16* __restrict__ w1h,
    const float* __restrict__ b1, _Float16* __restrict__ h1p)
{
    __shared__ __align__(16) char smem[73728];     // all 9 taps x 128 oc x 32 k
    const int tid = threadIdx.x;
    const int wv = tid >> 6, lane = tid & 63;
    const int row16 = lane & 15, quad = lane >> 4;
    const int ptile = blockIdx.x;
    const int b = ptile >> 4;
    const int pim0 = (ptile & 15) << 8;
    const int h0 = pim0 >> 6;

#pragma unroll
    for (int k = 0; k < 18; ++k)                   // 4608 16B chunks
        ASYNC16(w1h + (size_t)(k * 256 + tid) * 8, smem + (k * 256 + wv * 64) * 16);

    f32x4 acc[4][8];
#pragma unroll
    for (int pt = 0; pt < 4; ++pt)
#pragma unroll
        for (int ot = 0; ot < 8; ++ot) acc[pt][ot] = (f32x4){0.f, 0.f, 0.f, 0.f};

    __syncthreads();
    const _Float16* wl = (const _Float16*)smem;

    for (int t = 0; t < 9; ++t) {
        const int dy = t / 3, dx = t % 3;
        const int pbase = (h0 + wv + dy) * 66 + dx + row16;
        half8 bf[4], af[8];
#pragma unroll
        for (int pt = 0; pt < 4; ++pt)
            bf[pt] = *(const half8*)(xh + XH_IDX(b, pbase + pt * 16) + quad * 8);
#pragma unroll
        for (int ot = 0; ot < 8; ++ot)
            af[ot] = *(const half8*)(wl + ((t * 128 + ot * 16 + row16) << 5) + quad * 8);
#pragma unroll
        for (int ot = 0; ot < 8; ++ot)
#pragma unroll
            for (int pt = 0; pt < 4; ++pt)
                acc[pt][ot] = __builtin_amdgcn_mfma_f32_16x16x32_f16(af[ot], bf[pt], acc[pt][ot], 0, 0, 0);
    }

    f32x4 bias[8];
#pragma unroll
    for (int ot = 0; ot < 8; ++ot) bias[ot] = *(const f32x4*)(b1 + ot * 16 + quad * 4);
#pragma unroll
    for (int pt = 0; pt < 4; ++pt) {
        const size_t pbase = ((size_t)((b << 12) + pim0 + wv * 64 + pt * 16 + row16)) << 7;
#pragma unroll
        for (int ot = 0; ot < 8; ++ot) {
            half4 v;
#pragma unroll
            for (int r = 0; r < 4; ++r)
                v[r] = (_Float16)fmaxf(acc[pt][ot][r] + bias[ot][r], 0.f);
            *(half4*)(h1p + pbase + ot * 16 + quad * 4) = v;
        }
    }
}

// ---------------------------------------------------------------------------
// conv2 as MFMA GEMM: M=pixels, N=128 oc, K=128. Whole w2 (32 KB fp16) in LDS.
// Epilogue also zeroes this image's h2p halo ring (zring folded in).
// ---------------------------------------------------------------------------
__global__ __launch_bounds__(256, 2) void conv2_k(
    const _Float16* __restrict__ h1p, const _Float16* __restrict__ w2h,
    const float* __restrict__ b2, _Float16* __restrict__ h2p)
{
    __shared__ __align__(16) char smem[33280];   // w2l 32768 + b2l 512
    float* b2l = (float*)(smem + 32768);
    const int tid = threadIdx.x;
    const int wv = tid >> 6, lane = tid & 63;
    const int row16 = lane & 15, quad = lane >> 4;
    const int ptile = blockIdx.x;
    const int b = ptile >> 4;
    const int pim0 = (ptile & 15) << 8;

    if (tid < 128) b2l[tid] = b2[tid];
#pragma unroll
    for (int k = 0; k < 8; ++k) {
        const int c0 = k * 256 + wv * 64;
        ASYNC16(w2h + (size_t)(c0 + lane) * 8, smem + c0 * 16);
    }

    f32x4 acc[4][8];
#pragma unroll
    for (int pt = 0; pt < 4; ++pt)
#pragma unroll
        for (int ot = 0; ot < 8; ++ot) acc[pt][ot] = (f32x4){0.f, 0.f, 0.f, 0.f};

    const int pixbase = (b << 12) + pim0 + wv * 64;
    __syncthreads();

#pragma unroll
    for (int ks = 0; ks < 4; ++ks) {
        half8 bf[4], af[8];
#pragma unroll
        for (int pt = 0; pt < 4; ++pt)
            bf[pt] = *(const half8*)(h1p + ((size_t)(pixbase + pt * 16 + row16) << 7) + ks * 32 + quad * 8);
        const _Float16* wl = (const _Float16*)smem;
#pragma unroll
        for (int ot = 0; ot < 8; ++ot)
            af[ot] = *(const half8*)(wl + ((ks * 128 + ot * 16 + row16) << 5) + quad * 8);
#pragma unroll
        for (int ot = 0; ot < 8; ++ot)
#pragma unroll
            for (int pt = 0; pt < 4; ++pt)
                acc[pt][ot] = __builtin_amdgcn_mfma_f32_16x16x32_f16(af[ot], bf[pt], acc[pt][ot], 0, 0, 0);
    }

#pragma unroll
    for (int pt = 0; pt < 4; ++pt) {
        const int p = pim0 + wv * 64 + pt * 16 + row16;      // within-image pixel
        const int pp = ((p >> 6) + 1) * 66 + (p & 63) + 1;
#pragma unroll
        for (int ot = 0; ot < 8; ++ot) {
            const int oc0 = ot * 16 + quad * 4;
            half4 v;
#pragma unroll
            for (int r = 0; r < 4; ++r)
                v[r] = (_Float16)fmaxf(acc[pt][ot][r] + b2l[oc0 + r], 0.f);
            *(half4*)(h2p + H2P_IDX(b, oc0 >> 5, pp) + (oc0 & 31)) = v;
        }
    }

    // ---- zero halo ring of this image's 4 h2p planes (4160 16B-chunks / 16 blocks) ----
    const int gidx = (ptile & 15) * 256 + tid;
    const f32x4 z = {0.f, 0.f, 0.f, 0.f};
#pragma unroll 1
    for (int u = gidx; u < 4160; u += 4096) {
        const int cc = u / 1040, r4 = u - cc * 1040;
        const int r = r4 >> 2, q = r4 & 3;
        int pp;
        if (r < 66)       pp = r;
        else if (r < 132) pp = 65 * 66 + (r - 66);
        else if (r < 196) pp = (r - 131) * 66;
        else              pp = (r - 195) * 66 + 65;
        *(f32x4*)(h2p + H2P_IDX(b, cc, pp) + q * 8) = z;
    }
}

// ---------------------------------------------------------------------------
// RQS spline evaluation for one element, given its 23 params in prm[].
// ---------------------------------------------------------------------------
__device__ __forceinline__ void rqs_eval(const float* prm, float xv,
                                         float& yv_out, float& lad_out)
{
    const float xin = fminf(fmaxf(xv, -3.f), 3.f);

    float mw = prm[0], mh = prm[8];
#pragma unroll
    for (int j = 1; j < 8; ++j) { mw = fmaxf(mw, prm[j]); mh = fmaxf(mh, prm[8 + j]); }
    float ew[8], eh[8];
    float sw = 0.f, sh = 0.f;
#pragma unroll
    for (int j = 0; j < 8; ++j) {
        ew[j] = expf(prm[j] - mw);      sw += ew[j];
        eh[j] = expf(prm[8 + j] - mh);  sh += eh[j];
    }
    const float rw = 1.f / sw, rh = 1.f / sh;

    const float CONST_D = logf(expf(0.999f) - 1.f);

    float cumw = 0.f, cumh = 0.f;
    float cw_lo = -3.f, ch_lo = -3.f;
    float in_cw = 0.f, in_w = 1.f, in_ch = 0.f, in_h = 1.f, sd0 = 0.f, sd1 = 0.f;
#pragma unroll
    for (int i = 0; i < 8; ++i) {
        cumw += fmaf(0.992f, ew[i] * rw, 0.001f);
        cumh += fmaf(0.992f, eh[i] * rh, 0.001f);
        const float cw_hi = (i == 7) ? 3.f : fmaf(6.f, cumw, -3.f);
        const float ch_hi = (i == 7) ? 3.f : fmaf(6.f, cumh, -3.f);
        const bool sel = (xin >= cw_lo) && ((i == 7) || (xin < cw_hi));
        in_cw = sel ? cw_lo : in_cw;
        in_w  = sel ? (cw_hi - cw_lo) : in_w;
        in_ch = sel ? ch_lo : in_ch;
        in_h  = sel ? (ch_hi - ch_lo) : in_h;
        sd0   = sel ? ((i == 0) ? CONST_D : prm[16 + i - 1]) : sd0;
        sd1   = sel ? ((i == 7) ? CONST_D : prm[16 + i]) : sd1;
        cw_lo = cw_hi; ch_lo = ch_hi;
    }

    const float d0 = 0.001f + ((sd0 > 20.f) ? sd0 : log1pf(expf(sd0)));
    const float d1 = 0.001f + ((sd1 > 20.f) ? sd1 : log1pf(expf(sd1)));

    const float delta = in_h / in_w;
    const float theta = (xin - in_cw) / in_w;
    const float omt = 1.f - theta;
    const float tom = theta * omt;
    const float th2 = theta * theta;
    const float numer = in_h * (delta * th2 + d0 * tom);
    const float denom = delta + (d0 + d1 - 2.f * delta) * tom;
    float yv = in_ch + numer / denom;
    const float dnum = delta * delta * (d1 * th2 + 2.f * delta * tom + d0 * omt * omt);
    float lad = logf(dnum) - 2.f * logf(denom);

    const bool inside = (xv >= -3.f) && (xv <= 3.f);
    yv_out = inside ? yv : xv;
    lad_out = inside ? lad : 0.f;
}

// ---------------------------------------------------------------------------
// conv3 v7: 4x6 tile (96 oc per wave, col 0..2) -> acc 96 regs -> 3 waves/SIMD
// (__launch_bounds__(256,3)); XOR-swizzled LDS staging on both act and wt
// kills the 64B-stride bank conflicts. Both operands from LDS; epilogue fully
// unrolled (constant acc indices — spill trap from rounds 3/5).
// GEMM: M=pixels (tile 256), N=96 oc' (of 288), K=1152 (9 t x 128 ci)
// ---------------------------------------------------------------------------
__global__ __launch_bounds__(256, 3) void conv3_rqs_k(
    const _Float16* __restrict__ h2p, const _Float16* __restrict__ w3h,
    const float* __restrict__ b3, const float* __restrict__ x,
    float* __restrict__ y, float* __restrict__ ld_out)
{
    __shared__ __align__(16) char smem[38016];
    // act [0,25344)  wt0 [25344,31488)  wt1 [31488,37632)  b3l [37632,38016)
    // epilogue overlay: epi 4 waves x 1600 floats = [0,25600)
    float* b3l = (float*)(smem + 37632);

    const int tid = threadIdx.x;
    const int wv = tid >> 6, lane = tid & 63;
    const int row16 = lane & 15, quad = lane >> 4;
    const int col = blockIdx.x;            // 0..2 -> oc' base col*96, ch col*4..+3
    const int ptile = blockIdx.y;
    const int b = ptile >> 4;
    const int pim0 = (ptile & 15) << 8;
    const int h0 = pim0 >> 6;              // base output row, multiple of 4

    if (tid < 96) {
        const int c = tid / 24, j = tid % 24;
        b3l[tid] = (j < 23) ? b3[(col * 4 + c) * 23 + j] : 0.f;
    }

    f32x4 acc[4][6];
#pragma unroll
    for (int pt = 0; pt < 4; ++pt)
#pragma unroll
        for (int ot = 0; ot < 6; ++ot) acc[pt][ot] = (f32x4){0.f, 0.f, 0.f, 0.f};

    // ---- staging (XOR-swizzled source; LDS dest contiguous per HW rule) ----
    auto stage_wt = [&](int t, int cc, int buf) {
        const _Float16* g = w3h + ((size_t)((t * 4 + cc) * 288 + col * 96) << 5);
        char* wb = smem + 25344 + buf * 6144;            // 384 chunks of 16B
        ASYNC16(g + (size_t)swz(tid) * 8, wb + wv * 64 * 16);
        if (wv < 2)
            ASYNC16(g + (size_t)swz(256 + wv * 64 + lane) * 8, wb + (256 + wv * 64) * 16);
    };
    auto stage_act = [&](int cc) {
        const _Float16* ga = h2p + H2P_IDX(b, cc, h0 * 66);   // 1584 chunks
#pragma unroll
        for (int k = 0; k < 6; ++k)
            ASYNC16(ga + (size_t)swz(k * 256 + tid) * 8, smem + (k * 256 + wv * 64) * 16);
        if (wv == 0 && lane < 48)
            ASYNC16(ga + (size_t)swz(1536 + lane) * 8, smem + 1536 * 16);
    };

    stage_act(0);
    stage_wt(0, 0, 0);

    const int qxw = (quad ^ (row16 & 3)) << 3;           // wt read XOR (halfs)

    for (int cc = 0; cc < 4; ++cc) {
        for (int t = 0; t < 9; ++t) {
            const int step = cc * 9 + t;
            __syncthreads();               // staged data ready; other wt buf free
            if (step + 1 < 36)
                stage_wt((t == 8) ? 0 : t + 1, (t == 8) ? cc + 1 : cc, (step + 1) & 1);
            const _Float16* act = (const _Float16*)smem;
            const _Float16* wt = (const _Float16*)(smem + 25344 + (step & 1) * 6144);
            const int dy = t / 3, dx = t % 3;
            const int lpp = (wv + dy) * 66 + dx + row16;
            const int qxa = (quad ^ (lpp & 3)) << 3;     // act read XOR (halfs)
            half8 bf[4], af[6];
#pragma unroll
            for (int pt = 0; pt < 4; ++pt)
                bf[pt] = *(const half8*)(act + ((lpp + pt * 16) << 5) + qxa);
#pragma unroll
            for (int ot = 0; ot < 6; ++ot)
                af[ot] = *(const half8*)(wt + ((ot * 16 + row16) << 5) + qxw);
#pragma unroll
            for (int ot = 0; ot < 6; ++ot)
#pragma unroll
                for (int pt = 0; pt < 4; ++pt)
                    acc[pt][ot] = __builtin_amdgcn_mfma_f32_16x16x32_f16(af[ot], bf[pt], acc[pt][ot], 0, 0, 0);
            if (t == 8 && cc < 3) {
                __syncthreads();           // act buffer dead for all waves
                stage_act(cc + 1);
            }
        }
    }
    __syncthreads();   // K-loop LDS reads done; epi overlay safe

    // ---- epilogue: FULLY UNROLLED over pt (constant acc indices only) ----
    float* epi = (float*)smem + wv * 1600;     // 16 pix x 100-stride floats
    float lad_acc = 0.f;
#pragma unroll
    for (int pt = 0; pt < 4; ++pt) {
#pragma unroll
        for (int ot = 0; ot < 6; ++ot)
            *(f32x4*)(epi + row16 * 100 + ot * 16 + quad * 4) = acc[pt][ot];
        __syncthreads();
        {   // 64 lanes: 16 pix x 4 channels
            const int p16 = lane & 15, c = lane >> 4;     // c 0..3
            float prm[23];
#pragma unroll
            for (int j = 0; j < 23; ++j)
                prm[j] = epi[p16 * 100 + c * 24 + j] + b3l[c * 24 + j];
            const int tpix = wv * 64 + pt * 16 + p16;
            const size_t xi = (((size_t)(b * 12 + col * 4 + c)) << 12) + (pim0 + tpix);
            const float xv = x[xi];
            float yv, lad;
            rqs_eval(prm, xv, yv, lad);
            y[xi] = yv;
            lad_acc += lad;
        }
        __syncthreads();   // epi region reuse across pt
    }

#pragma unroll
    for (int off = 32; off > 0; off >>= 1) lad_acc += __shfl_down(lad_acc, off);
    if (lane == 0) atomicAdd(&ld_out[b], lad_acc);
}

// ---------------------------------------------------------------------------
extern "C" void kernel_launch(void* const* d_in, const int* in_sizes, int n_in,
                              void* d_out, int out_size, void* d_ws, size_t ws_size,
                              hipStream_t stream)
{
    const float* x      = (const float*)d_in[0];
    const float* logdet = (const float*)d_in[1];
    const float* cond   = (const float*)d_in[2];
    const float* w1     = (const float*)d_in[3];
    const float* b1     = (const float*)d_in[4];
    const float* w2     = (const float*)d_in[5];
    const float* b2     = (const float*)d_in[6];
    const float* w3     = (const float*)d_in[7];
    const float* b3     = (const float*)d_in[8];

    char* ws = (char*)d_ws;
    _Float16* h1p = (_Float16*)ws;                       // 33,554,432 B  [b][pix][128oc]
    _Float16* h2p = (_Float16*)(ws + 33554432);          // 35,684,352 B
    _Float16* xh  = (_Float16*)(ws + 33554432);          // 8,921,088 B — ALIASES h2p
                                                         // (consumed by conv1 before
                                                         //  conv2 writes h2p)
    _Float16* w1h = (_Float16*)(ws + 69238784);          // 73,728 B
    _Float16* w2h = (_Float16*)(ws + 69312512);          // 32,768 B
    _Float16* w3h = (_Float16*)(ws + 69345280);          // 663,552 B (end ~70 MB)

    float* y      = (float*)d_out;                       // NY floats
    float* ld_out = y + NY;                              // 32 floats

    setup_k<<<1296, 256, 0, stream>>>(w1, w2, w3, w1h, w2h, w3h, logdet, ld_out,
                                      x, cond, xh);
    conv1_k<<<512, 256, 0, stream>>>(xh, w1h, b1, h1p);
    conv2_k<<<512, 256, 0, stream>>>(h1p, w2h, b2, h2p);
    conv3_rqs_k<<<dim3(3, 512), 256, 0, stream>>>(h2p, w3h, b3, x, y, ld_out);
}

// Round 10
// 241.170 us; speedup vs baseline: 1.1164x; 1.1164x over previous
//
#include <hip/hip_runtime.h>
#include <math.h>

// B=32, C=12, H=64, W=64, hidden=128, cond_c=4, out_spline=276 (pad->288=12*24)
// NUM_BINS=8, TAIL=3.0, MBW=MBH=MD=0.001

#define NPIX 4096
#define NY   1572864

typedef _Float16 half8 __attribute__((ext_vector_type(8)));
typedef _Float16 half4 __attribute__((ext_vector_type(4)));
typedef float f32x4 __attribute__((ext_vector_type(4)));

// async global->LDS, 16B per lane: HW writes LDS base + lane*16; lds base wave-uniform
#define ASYNC16(gsrc, ldst) \
  __builtin_amdgcn_global_load_lds((const __attribute__((address_space(1))) unsigned int*)(gsrc), \
                                   (__attribute__((address_space(3))) unsigned int*)(ldst), 16, 0, 0)

// Tile-transpose source permutation (16B chunks): LDS slot tile*64+q*16+r holds
// global chunk tile*64+r*4+q  =>  wave fragment reads are CONTIGUOUS (no bank
// conflicts; the round-9 quad-XOR failed because 64B ROW STRIDE, not quad
// order, caused the 8-way conflicts).
__device__ __forceinline__ int gswt(int s) {
    return (s & ~63) | ((s & 15) << 2) | ((s >> 4) & 3);
}
// act plane-transpose: LDS slot q*396+p holds global chunk p*4+q (1584 chunks)
__device__ __forceinline__ int gsa(int s) {
    int q = s / 396, p = s - q * 396;
    return p * 4 + q;
}

// h2p layout: [b][cc=ci/32][pp=66*66][ci%32] fp16, halo ring of zeros
#define H2P_PLANE 4356            // 66*66
#define H2P_IDX(b, cc, pp) ((((size_t)(b) * 4 + (cc)) * H2P_PLANE + (pp)) << 5)
// xh layout: [b][pp=66*66][32] fp16 (ci<12 x, 12..15 cond, >=16 zero; halo zero)
#define XH_IDX(b, pp) (((size_t)(b) * H2P_PLANE + (pp)) << 5)

// ---------------------------------------------------------------------------
// setup: weight packs + logdet init + xh pack
// ---------------------------------------------------------------------------
__global__ __launch_bounds__(256) void setup_k(
    const float* __restrict__ w1, const float* __restrict__ w2,
    const float* __restrict__ w3, _Float16* __restrict__ w1h,
    _Float16* __restrict__ w2h, _Float16* __restrict__ w3h,
    const float* __restrict__ logdet, float* __restrict__ ld_out,
    const float* __restrict__ x, const float* __restrict__ cond,
    _Float16* __restrict__ xh)
{
    const int i = blockIdx.x * 256 + threadIdx.x;   // < 331776
    if (i < 36864) {                     // w1h[(t*128+oc)*32 + k]
        int k = i & 31, oc = (i >> 5) & 127, t = i >> 12;
        w1h[i] = (_Float16)((k < 16) ? w1[(oc * 16 + k) * 9 + t] : 0.f);
    }
    if (i < 16384) {                     // w2h[(ks*128+oc)*32 + km]
        int km = i & 31, oc = (i >> 5) & 127, ks = i >> 12;
        w2h[i] = (_Float16)w2[oc * 128 + ks * 32 + km];
    }
    {   // w3h[((t*4+cc)*288 + oc')*32 + cim], oc' = c*24+j
        int cim = i & 31;
        int oc = (i >> 5) % 288;
        int tc = i / (288 * 32);        // 0..35
        int t = tc >> 2, cc = tc & 3;
        int c = oc / 24, j = oc % 24;
        int ci = cc * 32 + cim;
        float v = (j < 23) ? w3[((c * 23 + j) * 128 + ci) * 9 + t] : 0.f;
        w3h[i] = (_Float16)v;
    }
    if (i < 32) ld_out[i] = logdet[i];
    if (i < 139392) {                    // xh pack (32*4356)
        const int b = i / H2P_PLANE, pp = i % H2P_PLANE;
        const int pr = pp / 66, pc = pp % 66;
        const bool interior = (pr >= 1) && (pr <= 64) && (pc >= 1) && (pc <= 64);
        _Float16 v[32];
#pragma unroll
        for (int ci = 0; ci < 32; ++ci) v[ci] = (_Float16)0.f;
        if (interior) {
            const int p = (pr - 1) * 64 + (pc - 1);
#pragma unroll
            for (int ci = 0; ci < 12; ++ci)
                v[ci] = (_Float16)x[((size_t)(b * 12 + ci) << 12) + p];
#pragma unroll
            for (int ci = 0; ci < 4; ++ci)
                v[12 + ci] = (_Float16)cond[((size_t)(b * 4 + ci) << 12) + p];
        }
        _Float16* dst = xh + ((size_t)i << 5);
#pragma unroll
        for (int q = 0; q < 4; ++q) *(f32x4*)(dst + q * 8) = *(f32x4*)(v + q * 8);
    }
}

// ---------------------------------------------------------------------------
// conv1 as implicit-GEMM MFMA: M=pixels, N=128 oc, K=9 taps x 32 (16 real ci).
// w1h (72 KB, 72 tiles) staged tile-transposed => conflict-free af reads.
// ---------------------------------------------------------------------------
__global__ __launch_bounds__(256, 2) void conv1_k(
    const _Float16* __restrict__ xh, const _Float16* __restrict__ w1h,
    const float* __restrict__ b1, _Float16* __restrict__ h1p)
{
    __shared__ __align__(16) char smem[73728];
    const int tid = threadIdx.x;
    const int wv = tid >> 6, lane = tid & 63;
    const int row16 = lane & 15, quad = lane >> 4;
    const int ptile = blockIdx.x;
    const int b = ptile >> 4;
    const int pim0 = (ptile & 15) << 8;
    const int h0 = pim0 >> 6;

#pragma unroll
    for (int k = 0; k < 18; ++k)                   // 4608 chunks, transposed
        ASYNC16(w1h + (size_t)gswt(k * 256 + tid) * 8, smem + (k * 256 + wv * 64) * 16);

    f32x4 acc[4][8];
#pragma unroll
    for (int pt = 0; pt < 4; ++pt)
#pragma unroll
        for (int ot = 0; ot < 8; ++ot) acc[pt][ot] = (f32x4){0.f, 0.f, 0.f, 0.f};

    __syncthreads();
    const _Float16* wl = (const _Float16*)smem;
    const int fro = ((quad << 4) | row16) * 8;     // fragment read offset (halfs)

    for (int t = 0; t < 9; ++t) {
        const int dy = t / 3, dx = t % 3;
        const int pbase = (h0 + wv + dy) * 66 + dx + row16;
        half8 bf[4], af[8];
#pragma unroll
        for (int pt = 0; pt < 4; ++pt)
            bf[pt] = *(const half8*)(xh + XH_IDX(b, pbase + pt * 16) + quad * 8);
#pragma unroll
        for (int ot = 0; ot < 8; ++ot)
            af[ot] = *(const half8*)(wl + ((t * 8 + ot) << 9) + fro);
#pragma unroll
        for (int ot = 0; ot < 8; ++ot)
#pragma unroll
            for (int pt = 0; pt < 4; ++pt)
                acc[pt][ot] = __builtin_amdgcn_mfma_f32_16x16x32_f16(af[ot], bf[pt], acc[pt][ot], 0, 0, 0);
    }

    f32x4 bias[8];
#pragma unroll
    for (int ot = 0; ot < 8; ++ot) bias[ot] = *(const f32x4*)(b1 + ot * 16 + quad * 4);
#pragma unroll
    for (int pt = 0; pt < 4; ++pt) {
        const size_t pbase = ((size_t)((b << 12) + pim0 + wv * 64 + pt * 16 + row16)) << 7;
#pragma unroll
        for (int ot = 0; ot < 8; ++ot) {
            half4 v;
#pragma unroll
            for (int r = 0; r < 4; ++r)
                v[r] = (_Float16)fmaxf(acc[pt][ot][r] + bias[ot][r], 0.f);
            *(half4*)(h1p + pbase + ot * 16 + quad * 4) = v;
        }
    }
}

// ---------------------------------------------------------------------------
// conv2 as MFMA GEMM: M=pixels, N=128 oc, K=128. w2 (32 KB, 32 tiles) staged
// tile-transposed => conflict-free af reads. Halo-ring zeroing folded in.
// ---------------------------------------------------------------------------
__global__ __launch_bounds__(256, 2) void conv2_k(
    const _Float16* __restrict__ h1p, const _Float16* __restrict__ w2h,
    const float* __restrict__ b2, _Float16* __restrict__ h2p)
{
    __shared__ __align__(16) char smem[33280];   // w2l 32768 + b2l 512
    float* b2l = (float*)(smem + 32768);
    const int tid = threadIdx.x;
    const int wv = tid >> 6, lane = tid & 63;
    const int row16 = lane & 15, quad = lane >> 4;
    const int ptile = blockIdx.x;
    const int b = ptile >> 4;
    const int pim0 = (ptile & 15) << 8;

    if (tid < 128) b2l[tid] = b2[tid];
#pragma unroll
    for (int k = 0; k < 8; ++k)                    // 2048 chunks, transposed
        ASYNC16(w2h + (size_t)gswt(k * 256 + tid) * 8, smem + (k * 256 + wv * 64) * 16);

    f32x4 acc[4][8];
#pragma unroll
    for (int pt = 0; pt < 4; ++pt)
#pragma unroll
        for (int ot = 0; ot < 8; ++ot) acc[pt][ot] = (f32x4){0.f, 0.f, 0.f, 0.f};

    const int pixbase = (b << 12) + pim0 + wv * 64;
    const int fro = ((quad << 4) | row16) * 8;
    __syncthreads();

#pragma unroll
    for (int ks = 0; ks < 4; ++ks) {
        half8 bf[4], af[8];
#pragma unroll
        for (int pt = 0; pt < 4; ++pt)
            bf[pt] = *(const half8*)(h1p + ((size_t)(pixbase + pt * 16 + row16) << 7) + ks * 32 + quad * 8);
        const _Float16* wl = (const _Float16*)smem;
#pragma unroll
        for (int ot = 0; ot < 8; ++ot)
            af[ot] = *(const half8*)(wl + ((ks * 8 + ot) << 9) + fro);
#pragma unroll
        for (int ot = 0; ot < 8; ++ot)
#pragma unroll
            for (int pt = 0; pt < 4; ++pt)
                acc[pt][ot] = __builtin_amdgcn_mfma_f32_16x16x32_f16(af[ot], bf[pt], acc[pt][ot], 0, 0, 0);
    }

#pragma unroll
    for (int pt = 0; pt < 4; ++pt) {
        const int p = pim0 + wv * 64 + pt * 16 + row16;      // within-image pixel
        const int pp = ((p >> 6) + 1) * 66 + (p & 63) + 1;
#pragma unroll
        for (int ot = 0; ot < 8; ++ot) {
            const int oc0 = ot * 16 + quad * 4;
            half4 v;
#pragma unroll
            for (int r = 0; r < 4; ++r)
                v[r] = (_Float16)fmaxf(acc[pt][ot][r] + b2l[oc0 + r], 0.f);
            *(half4*)(h2p + H2P_IDX(b, oc0 >> 5, pp) + (oc0 & 31)) = v;
        }
    }

    // ---- zero halo ring of this image's 4 h2p planes ----
    const int gidx = (ptile & 15) * 256 + tid;
    const f32x4 z = {0.f, 0.f, 0.f, 0.f};
#pragma unroll 1
    for (int u = gidx; u < 4160; u += 4096) {
        const int cc = u / 1040, r4 = u - cc * 1040;
        const int r = r4 >> 2, q = r4 & 3;
        int pp;
        if (r < 66)       pp = r;
        else if (r < 132) pp = 65 * 66 + (r - 66);
        else if (r < 196) pp = (r - 131) * 66;
        else              pp = (r - 195) * 66 + 65;
        *(f32x4*)(h2p + H2P_IDX(b, cc, pp) + q * 8) = z;
    }
}

// ---------------------------------------------------------------------------
// RQS spline evaluation for one element, given its 23 params in prm[].
// ---------------------------------------------------------------------------
__device__ __forceinline__ void rqs_eval(const float* prm, float xv,
                                         float& yv_out, float& lad_out)
{
    const float xin = fminf(fmaxf(xv, -3.f), 3.f);

    float mw = prm[0], mh = prm[8];
#pragma unroll
    for (int j = 1; j < 8; ++j) { mw = fmaxf(mw, prm[j]); mh = fmaxf(mh, prm[8 + j]); }
    float ew[8], eh[8];
    float sw = 0.f, sh = 0.f;
#pragma unroll
    for (int j = 0; j < 8; ++j) {
        ew[j] = expf(prm[j] - mw);      sw += ew[j];
        eh[j] = expf(prm[8 + j] - mh);  sh += eh[j];
    }
    const float rw = 1.f / sw, rh = 1.f / sh;

    const float CONST_D = logf(expf(0.999f) - 1.f);

    float cumw = 0.f, cumh = 0.f;
    float cw_lo = -3.f, ch_lo = -3.f;
    float in_cw = 0.f, in_w = 1.f, in_ch = 0.f, in_h = 1.f, sd0 = 0.f, sd1 = 0.f;
#pragma unroll
    for (int i = 0; i < 8; ++i) {
        cumw += fmaf(0.992f, ew[i] * rw, 0.001f);
        cumh += fmaf(0.992f, eh[i] * rh, 0.001f);
        const float cw_hi = (i == 7) ? 3.f : fmaf(6.f, cumw, -3.f);
        const float ch_hi = (i == 7) ? 3.f : fmaf(6.f, cumh, -3.f);
        const bool sel = (xin >= cw_lo) && ((i == 7) || (xin < cw_hi));
        in_cw = sel ? cw_lo : in_cw;
        in_w  = sel ? (cw_hi - cw_lo) : in_w;
        in_ch = sel ? ch_lo : in_ch;
        in_h  = sel ? (ch_hi - ch_lo) : in_h;
        sd0   = sel ? ((i == 0) ? CONST_D : prm[16 + i - 1]) : sd0;
        sd1   = sel ? ((i == 7) ? CONST_D : prm[16 + i]) : sd1;
        cw_lo = cw_hi; ch_lo = ch_hi;
    }

    const float d0 = 0.001f + ((sd0 > 20.f) ? sd0 : log1pf(expf(sd0)));
    const float d1 = 0.001f + ((sd1 > 20.f) ? sd1 : log1pf(expf(sd1)));

    const float delta = in_h / in_w;
    const float theta = (xin - in_cw) / in_w;
    const float omt = 1.f - theta;
    const float tom = theta * omt;
    const float th2 = theta * theta;
    const float numer = in_h * (delta * th2 + d0 * tom);
    const float denom = delta + (d0 + d1 - 2.f * delta) * tom;
    float yv = in_ch + numer / denom;
    const float dnum = delta * delta * (d1 * th2 + 2.f * delta * tom + d0 * omt * omt);
    float lad = logf(dnum) - 2.f * logf(denom);

    const bool inside = (xv >= -3.f) && (xv <= 3.f);
    yv_out = inside ? yv : xv;
    lad_out = inside ? lad : 0.f;
}

// ---------------------------------------------------------------------------
// conv3 v8 = round-8 structure (2 cols x 144 oc, 4x9 tile, (256,2), both
// operands LDS-staged) + CONFLICT-FREE transposed layouts:
//   wt: 9 tiles, slot tile*64+q*16+r  -> af reads contiguous 1KB/wave
//   act: [q-plane][pixel], slot q*396+p -> bf reads contiguous 256B/quad
// Epilogue fully unrolled (constant acc indices — rounds-3/5 spill trap).
// ---------------------------------------------------------------------------
__global__ __launch_bounds__(256, 2) void conv3_rqs_k(
    const _Float16* __restrict__ h2p, const _Float16* __restrict__ w3h,
    const float* __restrict__ b3, const float* __restrict__ x,
    float* __restrict__ y, float* __restrict__ ld_out)
{
    __shared__ __align__(16) char smem[44352];
    // act [0,25344)  wt0 [25344,34560)  wt1 [34560,43776)  b3l [43776,44352)
    // epilogue overlay: epi 4 waves x 2368 floats = [0,37888)
    float* b3l = (float*)(smem + 43776);

    const int tid = threadIdx.x;
    const int wv = tid >> 6, lane = tid & 63;
    const int row16 = lane & 15, quad = lane >> 4;
    const int col = blockIdx.x;            // 0..1 -> oc' base col*144, ch col*6..+5
    const int ptile = blockIdx.y;
    const int b = ptile >> 4;
    const int pim0 = (ptile & 15) << 8;
    const int h0 = pim0 >> 6;              // base output row, multiple of 4

    if (tid < 144) {
        const int c = tid / 24, j = tid % 24;
        b3l[tid] = (j < 23) ? b3[(col * 6 + c) * 23 + j] : 0.f;
    }

    f32x4 acc[4][9];
#pragma unroll
    for (int pt = 0; pt < 4; ++pt)
#pragma unroll
        for (int ot = 0; ot < 9; ++ot) acc[pt][ot] = (f32x4){0.f, 0.f, 0.f, 0.f};

    // ---- staging: transposed source permutation, contiguous LDS dest ----
    auto stage_wt = [&](int t, int cc, int buf) {
        const _Float16* g = w3h + ((size_t)((t * 4 + cc) * 288 + col * 144) << 5);
        char* wb = smem + 25344 + buf * 9216;            // 576 chunks (9 tiles)
        ASYNC16(g + (size_t)gswt(tid) * 8, wb + wv * 64 * 16);
        ASYNC16(g + (size_t)gswt(256 + tid) * 8, wb + (256 + wv * 64) * 16);
        if (wv == 0) ASYNC16(g + (size_t)gswt(512 + lane) * 8, wb + 512 * 16);
    };
    auto stage_act = [&](int cc) {
        const _Float16* ga = h2p + H2P_IDX(b, cc, h0 * 66);   // 1584 chunks
#pragma unroll
        for (int k = 0; k < 6; ++k)
            ASYNC16(ga + (size_t)gsa(k * 256 + tid) * 8, smem + (k * 256 + wv * 64) * 16);
        if (wv == 0 && lane < 48)
            ASYNC16(ga + (size_t)gsa(1536 + lane) * 8, smem + 1536 * 16);
    };

    stage_act(0);
    stage_wt(0, 0, 0);

    const int fro = ((quad << 4) | row16) * 8;     // wt fragment read offset (halfs)

    for (int cc = 0; cc < 4; ++cc) {
        for (int t = 0; t < 9; ++t) {
            const int step = cc * 9 + t;
            __syncthreads();               // staged data ready; other wt buf free
            if (step + 1 < 36)
                stage_wt((t == 8) ? 0 : t + 1, (t == 8) ? cc + 1 : cc, (step + 1) & 1);
            const _Float16* act = (const _Float16*)smem;
            const _Float16* wt = (const _Float16*)(smem + 25344 + (step & 1) * 9216);
            const int dy = t / 3, dx = t % 3;
            const int lpp = quad * 396 + (wv + dy) * 66 + dx + row16;   // [q][p]
            half8 bf[4], af[9];
#pragma unroll
            for (int pt = 0; pt < 4; ++pt)
                bf[pt] = *(const half8*)(act + (lpp + pt * 16) * 8);
#pragma unroll
            for (int ot = 0; ot < 9; ++ot)
                af[ot] = *(const half8*)(wt + (ot << 9) + fro);
#pragma unroll
            for (int ot = 0; ot < 9; ++ot)
#pragma unroll
                for (int pt = 0; pt < 4; ++pt)
                    acc[pt][ot] = __builtin_amdgcn_mfma_f32_16x16x32_f16(af[ot], bf[pt], acc[pt][ot], 0, 0, 0);
            if (t == 8 && cc < 3) {
                __syncthreads();           // act buffer dead for all waves
                stage_act(cc + 1);
            }
        }
    }
    __syncthreads();   // K-loop LDS reads done; epi overlay safe

    // ---- epilogue: FULLY UNROLLED over pt (constant acc indices only) ----
    float* epi = (float*)smem + wv * 2368;     // 16 pix x 148-stride floats
    float lad_acc = 0.f;
#pragma unroll
    for (int pt = 0; pt < 4; ++pt) {
#pragma unroll
        for (int ot = 0; ot < 9; ++ot)
            *(f32x4*)(epi + row16 * 148 + ot * 16 + quad * 4) = acc[pt][ot];
        __syncthreads();
#pragma unroll 1
        for (int pass = 0; pass < 2; ++pass) {
            const int idx = pass * 64 + lane;
            if (idx < 96) {
                const int p16 = idx & 15, c = idx >> 4;       // c 0..5
                float prm[23];
#pragma unroll
                for (int j = 0; j < 23; ++j)
                    prm[j] = epi[p16 * 148 + c * 24 + j] + b3l[c * 24 + j];
                const int tpix = wv * 64 + pt * 16 + p16;
                const size_t xi = (((size_t)(b * 12 + col * 6 + c)) << 12) + (pim0 + tpix);
                const float xv = x[xi];
                float yv, lad;
                rqs_eval(prm, xv, yv, lad);
                y[xi] = yv;
                lad_acc += lad;
            }
        }
        __syncthreads();   // epi region reuse across pt
    }

#pragma unroll
    for (int off = 32; off > 0; off >>= 1) lad_acc += __shfl_down(lad_acc, off);
    if (lane == 0) atomicAdd(&ld_out[b], lad_acc);
}

// ---------------------------------------------------------------------------
extern "C" void kernel_launch(void* const* d_in, const int* in_sizes, int n_in,
                              void* d_out, int out_size, void* d_ws, size_t ws_size,
                              hipStream_t stream)
{
    const float* x      = (const float*)d_in[0];
    const float* logdet = (const float*)d_in[1];
    const float* cond   = (const float*)d_in[2];
    const float* w1     = (const float*)d_in[3];
    const float* b1     = (const float*)d_in[4];
    const float* w2     = (const float*)d_in[5];
    const float* b2     = (const float*)d_in[6];
    const float* w3     = (const float*)d_in[7];
    const float* b3     = (const float*)d_in[8];

    char* ws = (char*)d_ws;
    _Float16* h1p = (_Float16*)ws;                       // 33,554,432 B  [b][pix][128oc]
    _Float16* h2p = (_Float16*)(ws + 33554432);          // 35,684,352 B
    _Float16* xh  = (_Float16*)(ws + 33554432);          // ALIASES h2p (consumed by
                                                         //  conv1 before conv2 writes)
    _Float16* w1h = (_Float16*)(ws + 69238784);          // 73,728 B
    _Float16* w2h = (_Float16*)(ws + 69312512);          // 32,768 B
    _Float16* w3h = (_Float16*)(ws + 69345280);          // 663,552 B (end ~70 MB)

    float* y      = (float*)d_out;                       // NY floats
    float* ld_out = y + NY;                              // 32 floats

    setup_k<<<1296, 256, 0, stream>>>(w1, w2, w3, w1h, w2h, w3h, logdet, ld_out,
                                      x, cond, xh);
    conv1_k<<<512, 256, 0, stream>>>(xh, w1h, b1, h1p);
    conv2_k<<<512, 256, 0, stream>>>(h1p, w2h, b2, h2p);
    conv3_rqs_k<<<dim3(2, 512), 256, 0, stream>>>(h2p, w3h, b3, x, y, ld_out);
}